// Round 4
// baseline (628.810 us; speedup 1.0000x reference)
//
#include <hip/hip_runtime.h>

// QRNN-fo layer. Dtype model v3: inputs FP32, output FP32.
//
// Pipeline:
//   K0a: X fp32->bf16 into d_out's H region (64 MiB; consumed by GEMM)
//   K0b: W fp32->bf16 into ws after Y
//   K1 : bf16 MFMA GEMM Y'' = act(X @ W^T + b), SCAN-TILED layout (round 7):
//        Y''[(s>>4)*3 + gate][chain][s&15], chain = b*1024+d, bf16.
//        GEMM body = round-2 kernel (measured 288 us); only epilogue changed.
//   K2 : scan pass1  — per-chunk affine summaries (A,B), 32 chunks of 64
//   K3 : combine     — 32-step composition -> chunk entry states + C_last
//   K4 : scan pass2  — exact recurrence from chunk entry, writes H
//
// Round-7 rationale: scans stuck at ~2.1 TB/s across width/waves/depth
// changes -> limiter is the 96-KiB-strided access pattern. New layout makes
// every scan load a contiguous ds/b128 stream (m13 copy pattern).

#define S_LEN 2048
#define BATCH 16
#define DHID 1024
#define N3 3072               // 3*DHID
#define MROWS (S_LEN * BATCH) // 32768
#define XELEMS ((size_t)MROWS * DHID)   // 33,554,432
#define WELEMS ((size_t)N3 * DHID)      //  3,145,728
#define YELEMS ((size_t)MROWS * N3)     // 100,663,296

typedef __attribute__((ext_vector_type(8))) short bf16x8;
typedef __attribute__((ext_vector_type(4))) float floatx4;
typedef __attribute__((ext_vector_type(4))) unsigned short u16x4;

__device__ __forceinline__ float b2f(unsigned short u) {
  return __uint_as_float(((unsigned)u) << 16);
}
__device__ __forceinline__ unsigned short f2b(float x) {
  unsigned u = __float_as_uint(x);
  u += 0x7fffu + ((u >> 16) & 1u);   // round-to-nearest-even
  return (unsigned short)(u >> 16);
}
__device__ __forceinline__ float sigmoid_f(float x) {
  return __builtin_amdgcn_rcpf(1.0f + __expf(-x));
}
__device__ __forceinline__ float tanh_f(float x) {
  return 2.0f * __builtin_amdgcn_rcpf(1.0f + __expf(-2.0f * x)) - 1.0f;
}

__device__ __forceinline__ void load_lds16(const unsigned short* g, unsigned short* l) {
  __builtin_amdgcn_global_load_lds(
      (const __attribute__((address_space(1))) void*)g,
      (__attribute__((address_space(3))) void*)l,
      16, 0, 0);
}

// ---------------------------------------------------------------------------
// fp32 -> bf16 converter (vectorized, n multiple of 4)
// ---------------------------------------------------------------------------
__global__ __launch_bounds__(256) void cvt_f32_bf16(
    const float* __restrict__ src, unsigned short* __restrict__ dst, int n4) {
  int i = blockIdx.x * 256 + threadIdx.x;
  if (i < n4) {
    float4 v = ((const float4*)src)[i];
    u16x4 o;
    o.x = f2b(v.x); o.y = f2b(v.y); o.z = f2b(v.z); o.w = f2b(v.w);
    ((u16x4*)dst)[i] = o;
  }
}

// ---------------------------------------------------------------------------
// GEMM: 128x128 block tile, 4 waves (2x2), each wave 64x64 via 4x4 MFMA
// 16x16x32. BK=64, single-buffered LDS via global_load_lds width 16 (m97
// structure, measured 288 us round 2). Epilogue writes the scan-tiled Y''.
// ---------------------------------------------------------------------------
__global__ __launch_bounds__(256) void qrnn_gemm(
    const unsigned short* __restrict__ X,    // (32768,1024) bf16 (converted)
    const unsigned short* __restrict__ W,    // (3072,1024)  bf16 (converted)
    const float* __restrict__ bias,          // (3072)       fp32
    unsigned short* __restrict__ Y)          // Y'' tiled bf16 (192 MiB)
{
  __shared__ __align__(16) unsigned short sA[128 * 64];
  __shared__ __align__(16) unsigned short sB[128 * 64];

  const int tid = threadIdx.x;
  const int w  = tid >> 6;     // wave 0..3
  const int l  = tid & 63;     // lane
  const int lr = l & 15;
  const int lq = l >> 4;
  const int n0B = blockIdx.x * 128;
  const int m0B = blockIdx.y * 128;
  const int wm = (w >> 1) * 64;
  const int wn = (w & 1) * 64;

  floatx4 acc[4][4] = {};

  const unsigned short* gA = X + (size_t)m0B * DHID;
  const unsigned short* gB = W + (size_t)n0B * DHID;
  const int srow = tid >> 3;           // 0..31 within 32-row chunk
  const int scol = (tid & 7) << 3;     // 0..56 step 8 shorts (16 B)

  for (int k0 = 0; k0 < DHID; k0 += 64) {
#pragma unroll
    for (int j = 0; j < 4; ++j) {
      // LDS dest = wave-uniform base + lane*16B; linear chunk order equals
      // [row][k] row-major, no padding.
      load_lds16(gA + (size_t)(j * 32 + srow) * DHID + (k0 + scol),
                 sA + (j * 2048 + w * 512));
      load_lds16(gB + (size_t)(j * 32 + srow) * DHID + (k0 + scol),
                 sB + (j * 2048 + w * 512));
    }
    __syncthreads();

#pragma unroll
    for (int kk = 0; kk < 64; kk += 32) {
      bf16x8 af[4], bf[4];
#pragma unroll
      for (int i = 0; i < 4; ++i) {
        af[i] = *(const bf16x8*)&sA[(wm + i * 16 + lr) * 64 + kk + lq * 8];
      }
#pragma unroll
      for (int j = 0; j < 4; ++j) {
        bf[j] = *(const bf16x8*)&sB[(wn + j * 16 + lr) * 64 + kk + lq * 8];
      }
#pragma unroll
      for (int i = 0; i < 4; ++i) {
#pragma unroll
        for (int j = 0; j < 4; ++j) {
          acc[i][j] = __builtin_amdgcn_mfma_f32_16x16x32_bf16(
              af[i], bf[j], acc[i][j], 0, 0, 0);
        }
      }
    }
    __syncthreads();
  }

  // Epilogue -> Y''. C/D layout: col = lane&15, row = quad*4 + reg (m89/m91).
  // m-row = s*16 + b. Within a wave half: srow_base = (m0B+wm)>>4 (mult of 4),
  // i adds +1 to srow (lq*4+r never carries past 16) -> the 4 acc[i] values
  // of fixed (j,r) are 4 consecutive s_in of ONE chain -> one 8-B store.
  const int gate = n0B >> 10;   // 0:Z(tanh) 1:F(sigmoid) 2:O(sigmoid)
  const int srow_base = (m0B + wm) >> 4;      // multiple of 4
  const int sblk = srow_base >> 4;
  const int sin0 = srow_base & 15;            // in {0,4,8,12}
  const size_t plane = (size_t)(sblk * 3 + gate) << 18;   // *262144
#pragma unroll
  for (int j = 0; j < 4; ++j) {
    const int n = n0B + wn + j * 16 + lr;
    const float bv = bias[n];
    const int dcol = n & 1023;
#pragma unroll
    for (int r = 0; r < 4; ++r) {
      const int chain = ((lq * 4 + r) << 10) | dcol;   // b*1024 + d
      u16x4 pk;
#pragma unroll
      for (int i = 0; i < 4; ++i) {
        float v = acc[i][j][r] + bv;
        v = (gate == 0) ? tanh_f(v) : sigmoid_f(v);
        pk[i] = f2b(v);
      }
      *(u16x4*)&Y[plane + ((size_t)chain << 4) + sin0] = pk;
    }
  }
}

// ---------------------------------------------------------------------------
// Chunked parallel scan over the tiled Y'' layout.
// c_t = f*z + (1-f)*c is linear in c: over a chunk, c_out = A*c_in + B.
// PCH=32 chunks of LCH=64 steps; 524288 threads (8192 waves, 32/CU).
// All Y reads are contiguous bf16x8 (16 B) loads: plane base + chain*16.
// ---------------------------------------------------------------------------
#define PCH 32
#define LCH (S_LEN / PCH)          // 64 steps, = 4 s_blks of 16
#define HSTRIDE (BATCH * DHID)     // 16384
#define NT (BATCH * DHID)          // 16384 chains

// pass1: per-(chain,chunk) affine summary (A,B). Reads Z,F planes only.
__global__ __launch_bounds__(256) void qrnn_scan_pass1(
    const unsigned short* __restrict__ Y,
    float* __restrict__ Aarr,            // (PCH, NT)
    float* __restrict__ Barr)            // (PCH, NT)
{
  const int g = blockIdx.x * 256 + threadIdx.x;  // 0..524287
  const int c = g & (NT - 1);
  const int p = g >> 14;
  const size_t cb = (size_t)c << 4;

  float a = 1.0f, bv = 0.0f;
#pragma unroll
  for (int gi = 0; gi < 4; ++gi) {
    const size_t pl = ((size_t)((p * 4 + gi) * 3) << 18) + cb;
    bf16x8 z0 = *(const bf16x8*)&Y[pl];
    bf16x8 z1 = *(const bf16x8*)&Y[pl + 8];
    bf16x8 f0 = *(const bf16x8*)&Y[pl + (1 << 18)];
    bf16x8 f1 = *(const bf16x8*)&Y[pl + (1 << 18) + 8];
#pragma unroll
    for (int j = 0; j < 8; ++j) {
      float zv = b2f((unsigned short)z0[j]);
      float fv = b2f((unsigned short)f0[j]);
      a  = fmaf(-fv, a, a);
      bv = fmaf(fv, zv - bv, bv);
    }
#pragma unroll
    for (int j = 0; j < 8; ++j) {
      float zv = b2f((unsigned short)z1[j]);
      float fv = b2f((unsigned short)f1[j]);
      a  = fmaf(-fv, a, a);
      bv = fmaf(fv, zv - bv, bv);
    }
  }
  Aarr[g] = a;
  Barr[g] = bv;
}

// combine: sequential composition across the 32 chunk summaries per chain.
__global__ __launch_bounds__(256) void qrnn_combine(
    const float* __restrict__ Aarr,
    const float* __restrict__ Barr,
    const float* __restrict__ h0,        // (16,1024) fp32
    float* __restrict__ Cin,             // (PCH, NT)
    float* __restrict__ out)             // C_last at S*HSTRIDE + t
{
  const int t = blockIdx.x * 256 + threadIdx.x;  // 0..16383
  float c = h0[t];
#pragma unroll
  for (int p = 0; p < PCH; ++p) {
    Cin[p * NT + t] = c;
    c = fmaf(Aarr[p * NT + t], c, Barr[p * NT + t]);
  }
  out[(size_t)S_LEN * HSTRIDE + t] = c;  // C_last fp32
}

// pass2: exact per-step recurrence from chunk entry; h = o*c. Reads Z,F,O
// planes contiguously; writes H in (s, b, d) fp32 (256-B wave runs).
__global__ __launch_bounds__(256) void qrnn_scan_pass2(
    const unsigned short* __restrict__ Y,
    const float* __restrict__ Cin,       // (PCH, NT)
    float* __restrict__ out)             // H (2048,16,1024) fp32
{
  const int g = blockIdx.x * 256 + threadIdx.x;  // 0..524287
  const int c = g & (NT - 1);
  const int p = g >> 14;
  const size_t cb = (size_t)c << 4;
  float cst = Cin[g];
  float* hb = out + c;

#pragma unroll
  for (int gi = 0; gi < 4; ++gi) {
    const size_t pl = ((size_t)((p * 4 + gi) * 3) << 18) + cb;
    bf16x8 z0 = *(const bf16x8*)&Y[pl];
    bf16x8 z1 = *(const bf16x8*)&Y[pl + 8];
    bf16x8 f0 = *(const bf16x8*)&Y[pl + (1 << 18)];
    bf16x8 f1 = *(const bf16x8*)&Y[pl + (1 << 18) + 8];
    bf16x8 o0 = *(const bf16x8*)&Y[pl + (2 << 18)];
    bf16x8 o1 = *(const bf16x8*)&Y[pl + (2 << 18) + 8];
    const int s0 = p * LCH + gi * 16;
#pragma unroll
    for (int j = 0; j < 8; ++j) {
      float zv = b2f((unsigned short)z0[j]);
      float fv = b2f((unsigned short)f0[j]);
      float ov = b2f((unsigned short)o0[j]);
      cst = fmaf(fv, zv - cst, cst);
      hb[(size_t)(s0 + j) << 14] = ov * cst;
    }
#pragma unroll
    for (int j = 0; j < 8; ++j) {
      float zv = b2f((unsigned short)z1[j]);
      float fv = b2f((unsigned short)f1[j]);
      float ov = b2f((unsigned short)o1[j]);
      cst = fmaf(fv, zv - cst, cst);
      hb[(size_t)(s0 + 8 + j) << 14] = ov * cst;
    }
  }
}

// ---------------------------------------------------------------------------
extern "C" void kernel_launch(void* const* d_in, const int* in_sizes, int n_in,
                              void* d_out, int out_size, void* d_ws, size_t ws_size,
                              hipStream_t stream) {
  const float* X    = (const float*)d_in[0]; // (2048,16,1024) fp32
  const float* h0   = (const float*)d_in[1]; // (16,1024)      fp32
  const float* W    = (const float*)d_in[2]; // (3072,1024)    fp32
  const float* bias = (const float*)d_in[3]; // (3072)         fp32
  float* out = (float*)d_out;                // fp32 H ++ C_last (128.06 MiB)

  // ws: Y'' bf16 (192 MiB) ++ Wbf (6 MiB). Xbf (64 MiB) parks in d_out's H
  // region (first half), consumed by the GEMM before pass2 rewrites it.
  // Aarr/Barr (2 MB each) live in the TAIL of the H region (rows s>=1984):
  // written by pass1, read by combine, then overwritten by pass2's stores
  // (stream-ordered). Cin (2 MB) reuses the dead Wbf region.
  unsigned short* Ybf = (unsigned short*)d_ws;
  unsigned short* Wbf = Ybf + YELEMS;
  unsigned short* Xbf = (unsigned short*)out;
  float* Aarr = out + ((size_t)S_LEN * HSTRIDE - 2 * (size_t)PCH * NT);
  float* Barr = Aarr + (size_t)PCH * NT;
  float* CinA = (float*)Wbf;
  static_assert((size_t)PCH * NT * 4 <= (size_t)WELEMS * 2,
                "Cin must fit in Wbf region");
  static_assert(2 * (size_t)PCH * NT * 4 <= (size_t)64 * 1024 * 1024,
                "A/B tail must stay clear of Xbf half");

  cvt_f32_bf16<<<(int)(XELEMS / 4 + 255) / 256, 256, 0, stream>>>(X, Xbf, (int)(XELEMS / 4));
  cvt_f32_bf16<<<(int)(WELEMS / 4 + 255) / 256, 256, 0, stream>>>(W, Wbf, (int)(WELEMS / 4));
  qrnn_gemm<<<dim3(N3 / 128, MROWS / 128), 256, 0, stream>>>(Xbf, Wbf, bias, Ybf);
  qrnn_scan_pass1<<<dim3((PCH * NT) / 256), 256, 0, stream>>>(Ybf, Aarr, Barr);
  qrnn_combine<<<dim3(NT / 256), 256, 0, stream>>>(Aarr, Barr, h0, CinA, out);
  qrnn_scan_pass2<<<dim3((PCH * NT) / 256), 256, 0, stream>>>(Ybf, CinA, out);
}